// Round 9
// baseline (101.254 us; speedup 1.0000x reference)
//
#include <hip/hip_runtime.h>

#define N_FEAT 16
#define N_BASIS 4
#define GAMMA 10.0f
#define R_MAX 5.0f
#define INV_SQRT2 0.70710678118654752f

#define BUCKET 100        // nodes per bucket -> acc LDS 76.8KB + spos -> 2 blocks/CU, nbuck=500
#define CAP 2000          // per-bucket edge capacity (mean 1600, sigma 40 -> +10 sigma)
#define MAXB 512          // max buckets supported
#define SC_BLOCK 512
#define SC_EDGES 4096     // edges per scatter block (8 per thread)
#define ACC_BLOCK 512     // 8 waves per bucket

#define FXINV   (1.0f / 2097152.0f)   // 2^-21 (scale folded into exp2 arg as +21)
#define KC      (-GAMMA * 1.4426950408889634f)
#define BIAS21  21.0f

#if __has_builtin(__builtin_amdgcn_exp2f)
#define EXP2(x) __builtin_amdgcn_exp2f(x)
#else
#define EXP2(x) exp2f(x)
#endif

// ---------- 0. pack pos into float4 + zero bucket cursors ----------
__global__ void pack_pos4_kernel(const float* __restrict__ pos,
                                 float4* __restrict__ pos4,
                                 int* __restrict__ gcursor, int n, int nbuck) {
    int i = blockIdx.x * blockDim.x + threadIdx.x;
    if (i < n) pos4[i] = make_float4(pos[3 * i], pos[3 * i + 1], pos[3 * i + 2], 0.0f);
    if (i < nbuck) gcursor[i] = 0;
}

// ---------- 1. LDS-staged bucket scatter ----------
// packed edge P = (src<<16)|dst ; bucket = (P>>16)/BUCKET ; dst = P&0xFFFF
__global__ void bucket_scatter_kernel(const int* __restrict__ src,
                                      const int* __restrict__ dst,
                                      int* __restrict__ gcursor,
                                      int* __restrict__ sorted,
                                      int n_edges, int nbuck) {
    __shared__ int h[MAXB];      // exclusive scan offsets (local)
    __shared__ int cur[MAXB];    // local scatter cursors
    __shared__ int gbase[MAXB];  // global base for this block's runs
    __shared__ int pay[SC_EDGES];

    int t = threadIdx.x;
    int base_e = blockIdx.x * SC_EDGES;
    int nloc = n_edges - base_e;
    if (nloc > SC_EDGES) nloc = SC_EDGES;

    for (int i = t; i < nbuck; i += SC_BLOCK) h[i] = 0;
    __syncthreads();

    unsigned pk[8];
    bool ok[8];
#pragma unroll
    for (int r = 0; r < 8; ++r) {
        int i = t + r * SC_BLOCK;
        ok[r] = (i < nloc);
        unsigned s = ok[r] ? (unsigned)src[base_e + i] : 0u;
        unsigned d = ok[r] ? (unsigned)dst[base_e + i] : 0u;
        pk[r] = (s << 16) | d;
        if (ok[r]) atomicAdd(&h[s / BUCKET], 1);
    }
    __syncthreads();

    // exclusive scan of h[0..nbuck) by wave 0
    if (t < 64) {
        int run = 0;
        for (int base = 0; base < nbuck; base += 64) {
            int i = base + t;
            int v = (i < nbuck) ? h[i] : 0;
            int incl = v;
            for (int off = 1; off < 64; off <<= 1) {
                int y = __shfl_up(incl, off, 64);
                if (t >= off) incl += y;
            }
            if (i < nbuck) h[i] = run + incl - v;
            run += __shfl(incl, 63, 64);
        }
    }
    __syncthreads();
    for (int i = t; i < nbuck; i += SC_BLOCK) cur[i] = h[i];
    __syncthreads();

#pragma unroll
    for (int r = 0; r < 8; ++r) {
        if (ok[r]) {
            int b = (int)((pk[r] >> 16) / BUCKET);
            int p = atomicAdd(&cur[b], 1);
            pay[p] = (int)pk[r];
        }
    }
    __syncthreads();

    for (int b = t; b < nbuck; b += SC_BLOCK) {
        int c = cur[b] - h[b];
        gbase[b] = (c > 0) ? atomicAdd(&gcursor[b], c) : 0;
    }
    __syncthreads();

    for (int i = t; i < nloc; i += SC_BLOCK) {
        unsigned P = (unsigned)pay[i];
        int b = (int)((P >> 16) / BUCKET);
        int idx = gbase[b] + (i - h[b]);
        if (idx < CAP) sorted[b * CAP + idx] = (int)P;
    }
}

// ---------- 2. per-bucket accumulate: edge-per-lane phase A + readlane phase B ----------
__global__ __launch_bounds__(ACC_BLOCK, 4) void accumulate_kernel(
        const float4* __restrict__ pos4,
        const float* __restrict__ nfeat,
        const int* __restrict__ sorted,
        const int* __restrict__ gcursor,
        float* __restrict__ out,
        int n_nodes) {
    __shared__ int acc[BUCKET * 192];   // 76.8 KB fixed-point accumulator
    __shared__ float4 spos[BUCKET];     // src positions of this bucket

    int b = blockIdx.x;
    int t = threadIdx.x;
    int w = t >> 6;
    int lane = t & 63;
    int nbase = b * BUCKET;

    // zero acc (vectorized) + stage src positions
    int4* accv = (int4*)acc;
    for (int i = t; i < BUCKET * 192 / 4; i += ACC_BLOCK)
        accv[i] = make_int4(0, 0, 0, 0);
    if (t < BUCKET) {
        int g = nbase + t;
        spos[t] = (g < n_nodes) ? pos4[g] : make_float4(0.f, 0.f, 0.f, 0.f);
    }
    __syncthreads();

    int cnt = gcursor[b];
    if (cnt > CAP) cnt = CAP;
    const int* seg = sorted + b * CAP;

    int k = lane >> 4;
    int f = lane & 15;
    float center = (float)k * (R_MAX / (N_BASIS - 1));
    int* acc_lane = acc + lane;

    int batches = cnt >> 6;

    // --- pipelined: phase A of next batch issued before phase B of current ---
    unsigned En = 0;
    float4 pn = make_float4(0.f, 0.f, 0.f, 0.f);
    float4 psn = pn;
    int bi = w;
    if (bi < batches) {
        En = (unsigned)seg[(bi << 6) + lane];
        int d = En & 0xFFFF;
        int sl = (int)(En >> 16) - nbase;
        pn = pos4[d];
        psn = spos[sl];
    }
    while (bi < batches) {
        unsigned E = En;
        float4 p = pn, ps = psn;
        int nbi = bi + (ACC_BLOCK / 64);
        if (nbi < batches) {
            En = (unsigned)seg[(nbi << 6) + lane];
            int d = En & 0xFFFF;
            int sl = (int)(En >> 16) - nbase;
            pn = pos4[d];
            psn = spos[sl];
        }
        // phase A: per-lane edge scalars
        float dx = p.x - ps.x, dy = p.y - ps.y, dz = p.z - ps.z;
        float r2 = dx * dx + dy * dy + dz * dz;
        float inv = __builtin_amdgcn_rsqf(r2);
        float dist = r2 * inv;
        float ux = dx * inv, uy = dy * inv, uz = dz * inv;

        // phase B: 64 edges, broadcast via readlane (values land in SGPRs)
#pragma unroll
        for (int j = 0; j < 64; ++j) {
            int Ej = __builtin_amdgcn_readlane((int)E, j);
            float dsj = __int_as_float(
                __builtin_amdgcn_readlane(__float_as_int(dist), j));
            float uxj = __int_as_float(
                __builtin_amdgcn_readlane(__float_as_int(ux), j));
            float uyj = __int_as_float(
                __builtin_amdgcn_readlane(__float_as_int(uy), j));
            float uzj = __int_as_float(
                __builtin_amdgcn_readlane(__float_as_int(uz), j));
            int dj = Ej & 0xFFFF;
            int slj = (int)((unsigned)Ej >> 16) - nbase;
            float nf = nfeat[(dj << 4) + f];
            float tt = dsj - center;
            float bb = EXP2(fmaf(tt * tt, KC, BIAS21));  // bb * 2^21
            float val = bb * nf;
            int* ap = acc_lane + slj * 192;
            atomicAdd(ap,       (int)(uxj * val));
            atomicAdd(ap + 64,  (int)(uyj * val));
            atomicAdd(ap + 128, (int)(uzj * val));
        }
        bi = nbi;
    }

    // tail: wave-per-edge (old path)
    for (int e = (batches << 6) + w; e < cnt; e += ACC_BLOCK / 64) {
        unsigned P = (unsigned)seg[e];
        int d = P & 0xFFFF;
        int sl = (int)(P >> 16) - nbase;
        float4 ps = spos[sl];
        float4 p = pos4[d];
        float nf = nfeat[(d << 4) + f];
        float dx = p.x - ps.x, dy = p.y - ps.y, dz = p.z - ps.z;
        float r2 = dx * dx + dy * dy + dz * dz;
        float inv = __builtin_amdgcn_rsqf(r2);
        float tt = r2 * inv - center;
        float bb = EXP2(fmaf(tt * tt, KC, BIAS21));
        float vs = bb * nf * inv;
        int* ap = acc_lane + sl * 192;
        atomicAdd(ap,       (int)(dx * vs));
        atomicAdd(ap + 64,  (int)(dy * vs));
        atomicAdd(ap + 128, (int)(dz * vs));
    }

    __syncthreads();

    // writeout: fused _pos_to_rep
    for (int j = w; j < BUCKET; j += ACC_BLOCK / 64) {
        int g = nbase + j;
        if (g >= n_nodes) continue;
        float x = (float)acc[j * 192 + lane] * FXINV;
        float y = (float)acc[j * 192 + 64 + lane] * FXINV;
        float z = (float)acc[j * 192 + 128 + lane] * FXINV;
        size_t obase = (size_t)g * 192 + lane;
        float* re = out + obase;
        float* im = out + (size_t)n_nodes * 192 + obase;
        float xs = x * INV_SQRT2;
        float ys = -y * INV_SQRT2;
        re[0]   = xs;
        re[64]  = z;
        re[128] = -xs;
        im[0]   = ys;
        im[64]  = 0.0f;
        im[128] = ys;
    }
}

extern "C" void kernel_launch(void* const* d_in, const int* in_sizes, int n_in,
                              void* d_out, int out_size, void* d_ws, size_t ws_size,
                              hipStream_t stream) {
    const float* pos = (const float*)d_in[0];
    const float* nfeat = (const float*)d_in[1];
    const int* edge_idx = (const int*)d_in[2];

    int n_nodes = in_sizes[0] / 3;
    int n_edges = in_sizes[2] / 2;

    const int* src = edge_idx;
    const int* dst = edge_idx + n_edges;

    float* out = (float*)d_out;
    int nbuck = (n_nodes + BUCKET - 1) / BUCKET;

    // workspace layout (256B-aligned regions)
    char* ws = (char*)d_ws;
    size_t o = 0;
    auto alloc = [&](size_t bytes) {
        char* p = ws + o;
        o = (o + bytes + 255) & ~(size_t)255;
        return p;
    };
    int* gcursor = (int*)alloc((size_t)nbuck * 4);
    int* sorted  = (int*)alloc((size_t)nbuck * CAP * 4);
    float4* pos4 = (float4*)alloc((size_t)n_nodes * 16);

    {
        int mx = (n_nodes > nbuck) ? n_nodes : nbuck;
        pack_pos4_kernel<<<(mx + 255) / 256, 256, 0, stream>>>(pos, pos4, gcursor,
                                                               n_nodes, nbuck);
    }

    {
        int grid = (n_edges + SC_EDGES - 1) / SC_EDGES;
        bucket_scatter_kernel<<<grid, SC_BLOCK, 0, stream>>>(src, dst, gcursor, sorted,
                                                             n_edges, nbuck);
    }

    accumulate_kernel<<<nbuck, ACC_BLOCK, 0, stream>>>(pos4, nfeat, sorted, gcursor,
                                                       out, n_nodes);
}

// Round 10
// 65.713 us; speedup vs baseline: 1.5409x; 1.5409x over previous
//
#include <hip/hip_runtime.h>

#define N_FEAT 16
#define N_BASIS 4
#define GAMMA 10.0f
#define R_MAX 5.0f
#define INV_SQRT2 0.70710678118654752f

#define BUCKET 50         // nodes per bucket -> acc LDS 38.4KB -> 4 blocks/CU, nbuck=1000
#define CAP 1088          // per-bucket edge capacity (mean 800, sigma 28 -> +10 sigma)
#define MAXB 1024         // max buckets supported
#define SC_BLOCK 512
#define SC_EDGES 4096     // edges per scatter block (8 per thread)
#define ACC_BLOCK 512     // 8 waves per bucket

#define FXINV   (1.0f / 2097152.0f)   // 2^-21 (scale folded into exp2 arg as +21)
#define KC      (-GAMMA * 1.4426950408889634f)
#define BIAS21  21.0f

#if __has_builtin(__builtin_amdgcn_exp2f)
#define EXP2(x) __builtin_amdgcn_exp2f(x)
#else
#define EXP2(x) exp2f(x)
#endif

// ---------- 0. pack pos into float4 + zero bucket cursors ----------
__global__ void pack_pos4_kernel(const float* __restrict__ pos,
                                 float4* __restrict__ pos4,
                                 int* __restrict__ gcursor, int n, int nbuck) {
    int i = blockIdx.x * blockDim.x + threadIdx.x;
    if (i < n) pos4[i] = make_float4(pos[3 * i], pos[3 * i + 1], pos[3 * i + 2], 0.0f);
    if (i < nbuck) gcursor[i] = 0;
}

// ---------- 1. LDS-staged bucket scatter ----------
// packed edge P = (src<<16)|dst ; bucket = (P>>16)/BUCKET ; dst = P&0xFFFF
__global__ void bucket_scatter_kernel(const int* __restrict__ src,
                                      const int* __restrict__ dst,
                                      int* __restrict__ gcursor,
                                      int* __restrict__ sorted,
                                      int n_edges, int nbuck) {
    __shared__ int h[MAXB];      // exclusive scan offsets (local)
    __shared__ int cur[MAXB];    // local scatter cursors
    __shared__ int gbase[MAXB];  // global base for this block's runs
    __shared__ int pay[SC_EDGES];

    int t = threadIdx.x;
    int base_e = blockIdx.x * SC_EDGES;
    int nloc = n_edges - base_e;
    if (nloc > SC_EDGES) nloc = SC_EDGES;

    for (int i = t; i < nbuck; i += SC_BLOCK) h[i] = 0;
    __syncthreads();

    unsigned pk[8];
    bool ok[8];
#pragma unroll
    for (int r = 0; r < 8; ++r) {
        int i = t + r * SC_BLOCK;
        ok[r] = (i < nloc);
        unsigned s = ok[r] ? (unsigned)src[base_e + i] : 0u;
        unsigned d = ok[r] ? (unsigned)dst[base_e + i] : 0u;
        pk[r] = (s << 16) | d;
        if (ok[r]) atomicAdd(&h[s / BUCKET], 1);
    }
    __syncthreads();

    // exclusive scan of h[0..nbuck) by wave 0
    if (t < 64) {
        int run = 0;
        for (int base = 0; base < nbuck; base += 64) {
            int i = base + t;
            int v = (i < nbuck) ? h[i] : 0;
            int incl = v;
            for (int off = 1; off < 64; off <<= 1) {
                int y = __shfl_up(incl, off, 64);
                if (t >= off) incl += y;
            }
            if (i < nbuck) h[i] = run + incl - v;
            run += __shfl(incl, 63, 64);
        }
    }
    __syncthreads();
    for (int i = t; i < nbuck; i += SC_BLOCK) cur[i] = h[i];
    __syncthreads();

#pragma unroll
    for (int r = 0; r < 8; ++r) {
        if (ok[r]) {
            int b = (int)((pk[r] >> 16) / BUCKET);
            int p = atomicAdd(&cur[b], 1);
            pay[p] = (int)pk[r];
        }
    }
    __syncthreads();

    for (int b = t; b < nbuck; b += SC_BLOCK) {
        int c = cur[b] - h[b];
        gbase[b] = (c > 0) ? atomicAdd(&gcursor[b], c) : 0;
    }
    __syncthreads();

    for (int i = t; i < nloc; i += SC_BLOCK) {
        unsigned P = (unsigned)pay[i];
        int b = (int)((P >> 16) / BUCKET);
        int idx = gbase[b] + (i - h[b]);
        if (idx < CAP) sorted[b * CAP + idx] = (int)P;
    }
}

// ---------- 2. per-bucket accumulate: 16-lane group per edge, k-loop inside ----------
// lane = g*16 + f ; each group owns one edge of a 4-edge batch; scalar chain 16x
// redundant (not 64x). Node rows rotated by 16*sl to break ds_add bank conflicts.
__global__ __launch_bounds__(ACC_BLOCK) void accumulate_kernel(
        const float4* __restrict__ pos4,
        const float* __restrict__ nfeat,
        const int* __restrict__ sorted,
        const int* __restrict__ gcursor,
        float* __restrict__ out,
        int n_nodes) {
    __shared__ int acc[BUCKET * 192];   // 38.4 KB fixed-point accumulator
    __shared__ float4 spos[BUCKET];     // src positions of this bucket

    int b = blockIdx.x;
    int t = threadIdx.x;
    int w = t >> 6;
    int lane = t & 63;
    int g = lane >> 4;     // group 0..3
    int f = lane & 15;     // feature
    int nbase = b * BUCKET;

    // zero acc (vectorized) + stage src positions
    int4* accv = (int4*)acc;
    for (int i = t; i < BUCKET * 48; i += ACC_BLOCK)
        accv[i] = make_int4(0, 0, 0, 0);
    if (t < BUCKET) {
        int gn = nbase + t;
        spos[t] = (gn < n_nodes) ? pos4[gn] : make_float4(0.f, 0.f, 0.f, 0.f);
    }
    __syncthreads();

    int cnt = gcursor[b];
    if (cnt > CAP) cnt = CAP;
    const int* seg = sorted + b * CAP;

    int iters = (cnt + 3) >> 2;
    for (int it = w; it < iters; it += ACC_BLOCK / 64) {
        int e = (it << 2) + g;
        bool live = (e < cnt);
        unsigned E = live ? (unsigned)seg[e] : 0u;
        int d = E & 0xFFFF;
        int sl = live ? ((int)(E >> 16) - nbase) : 0;

        float4 p = pos4[d];                 // group-uniform 16B gather
        float nfv = nfeat[(d << 4) + f];    // 16 consecutive floats per group
        float4 ps = spos[sl];

        float dx = p.x - ps.x, dy = p.y - ps.y, dz = p.z - ps.z;
        float r2 = dx * dx + dy * dy + dz * dz;
        float inv = __builtin_amdgcn_rsqf(r2);
        float dist = r2 * inv;
        float nfi = nfv * inv;

        int rotbase = f + (sl << 4);        // logical word (16k+f) rotated by 16*sl
        int sl192 = sl * 192;
#pragma unroll
        for (int kk = 0; kk < N_BASIS; ++kk) {
            float ck = (float)kk * (R_MAX / (N_BASIS - 1));
            float tt = dist - ck;
            float bb = EXP2(fmaf(tt * tt, KC, BIAS21));  // basis * 2^21
            float val = live ? bb * nfi : 0.0f;          // kills NaN on dead lanes
            int* ap = acc + sl192 + ((rotbase + (kk << 4)) & 63);
            atomicAdd(ap,       (int)(dx * val));
            atomicAdd(ap + 64,  (int)(dy * val));
            atomicAdd(ap + 128, (int)(dz * val));
        }
    }

    __syncthreads();

    // writeout: fused _pos_to_rep (un-rotate with (lane + 16j) & 63)
    for (int j = w; j < BUCKET; j += ACC_BLOCK / 64) {
        int gn = nbase + j;
        if (gn >= n_nodes) continue;
        int rot = (lane + (j << 4)) & 63;
        int jb = j * 192;
        float x = (float)acc[jb + rot] * FXINV;
        float y = (float)acc[jb + 64 + rot] * FXINV;
        float z = (float)acc[jb + 128 + rot] * FXINV;
        size_t obase = (size_t)gn * 192 + lane;
        float* re = out + obase;
        float* im = out + (size_t)n_nodes * 192 + obase;
        float xs = x * INV_SQRT2;
        float ys = -y * INV_SQRT2;
        re[0]   = xs;
        re[64]  = z;
        re[128] = -xs;
        im[0]   = ys;
        im[64]  = 0.0f;
        im[128] = ys;
    }
}

extern "C" void kernel_launch(void* const* d_in, const int* in_sizes, int n_in,
                              void* d_out, int out_size, void* d_ws, size_t ws_size,
                              hipStream_t stream) {
    const float* pos = (const float*)d_in[0];
    const float* nfeat = (const float*)d_in[1];
    const int* edge_idx = (const int*)d_in[2];

    int n_nodes = in_sizes[0] / 3;
    int n_edges = in_sizes[2] / 2;

    const int* src = edge_idx;
    const int* dst = edge_idx + n_edges;

    float* out = (float*)d_out;
    int nbuck = (n_nodes + BUCKET - 1) / BUCKET;

    // workspace layout (256B-aligned regions)
    char* ws = (char*)d_ws;
    size_t o = 0;
    auto alloc = [&](size_t bytes) {
        char* p = ws + o;
        o = (o + bytes + 255) & ~(size_t)255;
        return p;
    };
    int* gcursor = (int*)alloc((size_t)nbuck * 4);
    int* sorted  = (int*)alloc((size_t)nbuck * CAP * 4);
    float4* pos4 = (float4*)alloc((size_t)n_nodes * 16);

    {
        int mx = (n_nodes > nbuck) ? n_nodes : nbuck;
        pack_pos4_kernel<<<(mx + 255) / 256, 256, 0, stream>>>(pos, pos4, gcursor,
                                                               n_nodes, nbuck);
    }

    {
        int grid = (n_edges + SC_EDGES - 1) / SC_EDGES;
        bucket_scatter_kernel<<<grid, SC_BLOCK, 0, stream>>>(src, dst, gcursor, sorted,
                                                             n_edges, nbuck);
    }

    accumulate_kernel<<<nbuck, ACC_BLOCK, 0, stream>>>(pos4, nfeat, sorted, gcursor,
                                                       out, n_nodes);
}